// Round 11
// baseline (514.022 us; speedup 1.0000x reference)
//
#include <hip/hip_runtime.h>
#include <hip/hip_bf16.h>

typedef __attribute__((ext_vector_type(8))) short short8;
typedef __attribute__((ext_vector_type(4))) short short4v;
typedef __attribute__((ext_vector_type(4))) float f32x4;
using u16 = unsigned short;

__device__ __forceinline__ u16 f2bf(float x) {
    __hip_bfloat16 h = __float2bfloat16(x);
    return *reinterpret_cast<u16*>(&h);
}

__device__ __forceinline__ void async16(void* lds, const void* g) {
    __builtin_amdgcn_global_load_lds((__attribute__((address_space(1))) void*)g,
                                     (__attribute__((address_space(3))) void*)lds,
                                     16, 0, 0);
}

// ---------------------------------------------------------------------------
// fp32 -> bf16 convert (weights only now), 8 elems/thread
// ---------------------------------------------------------------------------
__global__ __launch_bounds__(256)
void f32_to_bf16_kernel(const float* __restrict__ in, u16* __restrict__ out, long n) {
    long i = ((long)blockIdx.x * 256 + threadIdx.x) * 8;
    if (i + 8 > n) return;
    float4 a = *(const float4*)(in + i);
    float4 b = *(const float4*)(in + i + 4);
    short8 p;
    p[0] = (short)f2bf(a.x); p[1] = (short)f2bf(a.y);
    p[2] = (short)f2bf(a.z); p[3] = (short)f2bf(a.w);
    p[4] = (short)f2bf(b.x); p[5] = (short)f2bf(b.y);
    p[6] = (short)f2bf(b.z); p[7] = (short)f2bf(b.w);
    *(short8*)(out + i) = p;
}

// ---------------------------------------------------------------------------
// BT-GEMM: C[m][n] = scale * sum_k A[m][k]*B[n][k] (+ bias[n])
// A_F32: A is fp32, staged to LDS with on-the-fly bf16 convert (reg-staged
//        ds_write_b128 to the SAME LDS bytes the async16 path fills).
// TRANS_C: write C transposed as Vt[8][1024][2048] (V-proj only; grid z==1,
//          M=16384 spans batches, batch = row>>11).
// B always bf16, staged via global_load_lds width-16 (m97 structure).
// 128x128 tile, BK=32, 4 waves. M,N mult of 128; K mult of 32. z = batch.
// ---------------------------------------------------------------------------
template<bool A_F32, bool OUT_BF16, bool ADD_BIAS, bool TRANS_C>
__global__ __launch_bounds__(256, 2)
void gemm_bt_kernel(const void* __restrict__ Av, const u16* __restrict__ B,
                    void* __restrict__ Cv, const float* __restrict__ bias,
                    float scale, int M, int N, int K,
                    long Abatch, long Bbatch, long Cbatch)
{
    __shared__ u16 As[128 * 32];
    __shared__ u16 Bs[128 * 32];

    const int tid  = threadIdx.x;
    const int wid  = tid >> 6;
    const int lane = tid & 63;

    B += (long)blockIdx.z * Bbatch;

    const int bm = blockIdx.y * 128;
    const int bn = blockIdx.x * 128;

    const int wr = (wid >> 1) * 64;
    const int wc = (wid & 1) * 64;

    f32x4 acc[4][4] = {};

    // staging geometry: thread t covers LDS bytes [t*16, t*16+16) per 4KB
    // half (rows 0..63 then 64..127); row srow, k-elems [scol, scol+8).
    const int srow = tid >> 2;
    const int scol = (tid & 3) * 8;
    const u16*   aptrb = nullptr;
    const float* aptrf = nullptr;
    if constexpr (A_F32) {
        aptrf = (const float*)Av + (long)blockIdx.z * Abatch
                + (long)(bm + srow) * K + scol;
    } else {
        aptrb = (const u16*)Av + (long)blockIdx.z * Abatch
                + (long)(bm + srow) * K + scol;
    }
    const u16* bptr = B + (long)(bn + srow) * K + scol;
    char* asb = (char*)As + wid * 1024; // wave-uniform base (+lane*16 by HW)
    char* bsb = (char*)Bs + wid * 1024;

    const int lr = lane & 15;
    const int lk = (lane >> 4) * 8;

    const int nk = K >> 5;
    for (int kt = 0; kt < nk; ++kt) {
        const u16* bk = bptr + kt * 32;
        async16(bsb,        bk);
        async16(bsb + 4096, bk + (long)64 * K);
        if constexpr (A_F32) {
            const float* a0 = aptrf + kt * 32;
            float4 u0 = *(const float4*)a0;
            float4 u1 = *(const float4*)(a0 + 4);
            float4 w0 = *(const float4*)(a0 + (long)64 * K);
            float4 w1 = *(const float4*)(a0 + (long)64 * K + 4);
            short8 s0, s1;
            s0[0] = (short)f2bf(u0.x); s0[1] = (short)f2bf(u0.y);
            s0[2] = (short)f2bf(u0.z); s0[3] = (short)f2bf(u0.w);
            s0[4] = (short)f2bf(u1.x); s0[5] = (short)f2bf(u1.y);
            s0[6] = (short)f2bf(u1.z); s0[7] = (short)f2bf(u1.w);
            s1[0] = (short)f2bf(w0.x); s1[1] = (short)f2bf(w0.y);
            s1[2] = (short)f2bf(w0.z); s1[3] = (short)f2bf(w0.w);
            s1[4] = (short)f2bf(w1.x); s1[5] = (short)f2bf(w1.y);
            s1[6] = (short)f2bf(w1.z); s1[7] = (short)f2bf(w1.w);
            *(short8*)((char*)As + tid * 16)        = s0;
            *(short8*)((char*)As + 4096 + tid * 16) = s1;
        } else {
            const u16* ak = aptrb + kt * 32;
            async16(asb,        ak);
            async16(asb + 4096, ak + (long)64 * K);
        }
        __syncthreads();  // drains vmcnt (async16) + lgkmcnt (ds_write)

        short8 af[4], bfr[4];
        #pragma unroll
        for (int i = 0; i < 4; ++i)
            af[i] = *(const short8*)&As[(wr + i * 16 + lr) * 32 + lk];
        #pragma unroll
        for (int j = 0; j < 4; ++j)
            bfr[j] = *(const short8*)&Bs[(wc + j * 16 + lr) * 32 + lk];

        #pragma unroll
        for (int i = 0; i < 4; ++i)
            #pragma unroll
            for (int j = 0; j < 4; ++j)
                acc[i][j] = __builtin_amdgcn_mfma_f32_16x16x32_bf16(
                                af[i], bfr[j], acc[i][j], 0, 0, 0);
        __syncthreads();
    }

    // epilogue: C/D layout col=lane&15, row=(lane>>4)*4+reg  [m89 verified]
    const int r0 = (lane >> 4) * 4;
    const long crow = bm + wr + r0;
    const long ccol = bn + wc + lr;
    if constexpr (TRANS_C) {
        // V-proj: Vt[batch][feature=ccol][row]; batch = row>>11 (2048 rows/b).
        u16* C = (u16*)Cv;
        #pragma unroll
        for (int i = 0; i < 4; ++i) {
            const long row = crow + i * 16;          // mult of 4, one batch
            const long zb = row >> 11, rr = row & 2047;
            #pragma unroll
            for (int j = 0; j < 4; ++j) {
                float bb = 0.f;
                if constexpr (ADD_BIAS) bb = bias[ccol + j * 16];
                short4v pk;
                #pragma unroll
                for (int r = 0; r < 4; ++r)
                    pk[r] = (short)f2bf(acc[i][j][r] * scale + bb);
                *(short4v*)(C + zb * 2097152 + (ccol + j * 16) * 2048 + rr) = pk;
            }
        }
    } else if constexpr (OUT_BF16) {
        u16* C = (u16*)Cv + (long)blockIdx.z * Cbatch;
        #pragma unroll
        for (int i = 0; i < 4; ++i)
            #pragma unroll
            for (int j = 0; j < 4; ++j) {
                float bb = 0.f;
                if constexpr (ADD_BIAS) bb = bias[ccol + j * 16];
                #pragma unroll
                for (int r = 0; r < 4; ++r)
                    C[(crow + i * 16 + r) * (long)N + ccol + j * 16] =
                        f2bf(acc[i][j][r] * scale + bb);
            }
    } else {
        float* C = (float*)Cv + (long)blockIdx.z * Cbatch;
        #pragma unroll
        for (int i = 0; i < 4; ++i)
            #pragma unroll
            for (int j = 0; j < 4; ++j) {
                float bb = 0.f;
                if constexpr (ADD_BIAS) bb = bias[ccol + j * 16];
                #pragma unroll
                for (int r = 0; r < 4; ++r)
                    C[(crow + i * 16 + r) * (long)N + ccol + j * 16] =
                        acc[i][j][r] * scale + bb;
            }
    }
}

// ---------------------------------------------------------------------------
// row softmax over L=2048, one block per row, in-place fp32.
// ---------------------------------------------------------------------------
__global__ __launch_bounds__(256)
void softmax_kernel(float* __restrict__ S, int L) {
    const long base = (long)blockIdx.x * L;
    float* row = S + base;
    const int t = threadIdx.x;
    const int lane = t & 63, wid = t >> 6;

    float4 v0 = ((const float4*)row)[2 * t];
    float4 v1 = ((const float4*)row)[2 * t + 1];

    float m = fmaxf(fmaxf(fmaxf(v0.x, v0.y), fmaxf(v0.z, v0.w)),
                    fmaxf(fmaxf(v1.x, v1.y), fmaxf(v1.z, v1.w)));
    #pragma unroll
    for (int off = 32; off; off >>= 1) m = fmaxf(m, __shfl_xor(m, off));

    __shared__ float red[8];
    if (lane == 0) red[wid] = m;
    __syncthreads();
    m = fmaxf(fmaxf(red[0], red[1]), fmaxf(red[2], red[3]));

    v0.x = __expf(v0.x - m); v0.y = __expf(v0.y - m);
    v0.z = __expf(v0.z - m); v0.w = __expf(v0.w - m);
    v1.x = __expf(v1.x - m); v1.y = __expf(v1.y - m);
    v1.z = __expf(v1.z - m); v1.w = __expf(v1.w - m);

    float s = ((v0.x + v0.y) + (v0.z + v0.w)) + ((v1.x + v1.y) + (v1.z + v1.w));
    #pragma unroll
    for (int off = 32; off; off >>= 1) s += __shfl_xor(s, off);
    if (lane == 0) red[4 + wid] = s;
    __syncthreads();
    s = (red[4] + red[5]) + (red[6] + red[7]);

    const float inv = 1.0f / s;
    v0.x *= inv; v0.y *= inv; v0.z *= inv; v0.w *= inv;
    v1.x *= inv; v1.y *= inv; v1.z *= inv; v1.w *= inv;

    ((float4*)row)[2 * t]     = v0;
    ((float4*)row)[2 * t + 1] = v1;
}

// ---------------------------------------------------------------------------
// launch — peak workspace 56,623,104 bytes (u16 offsets below).
//   wqb@0  wkb@1,048,576  wvb@2,097,152
//   Qbf@3,145,728 (8,388,608)   [dead after QK]
//   Kbf@11,534,336 (16,777,216) [dead after QK]
//   Vt @3,145,728 (16,777,216)  [written after QK into dead Q/K region]
// P is never materialized: PV stages fp32 softmax output (d_out) with
// on-the-fly bf16 convert. Stream order makes alias hand-offs safe.
// ---------------------------------------------------------------------------
extern "C" void kernel_launch(void* const* d_in, const int* in_sizes, int n_in,
                              void* d_out, int out_size, void* d_ws, size_t ws_size,
                              hipStream_t stream) {
    const float* x  = (const float*)d_in[0];   // [8,2048,1024]
    const float* q  = (const float*)d_in[1];   // [8,1024,1024]
    const float* Wq = (const float*)d_in[2];
    const float* bq = (const float*)d_in[3];
    const float* Wk = (const float*)d_in[4];
    const float* bk = (const float*)d_in[5];
    const float* Wv = (const float*)d_in[6];
    const float* bv = (const float*)d_in[7];
    float* out = (float*)d_out;  // weighted [8,1024,1024] ++ attention [8,1024,2048]

    u16* ws  = (u16*)d_ws;
    u16* wqb = ws;
    u16* wkb = ws + 1048576;
    u16* wvb = ws + 2097152;
    u16* Qbf = ws + 3145728;    //  8,388,608 u16
    u16* Kbf = ws + 11534336;   // 16,777,216 u16
    u16* Vt  = ws + 3145728;    // 16,777,216 u16 (aliases dead Qbf+Kbf head)

    float* Sout = out + 8388608;  // attention region of d_out

    dim3 blk(256);

    // 1) weights -> bf16
    f32_to_bf16_kernel<<<512, blk, 0, stream>>>(Wq, wqb, 1048576L);
    f32_to_bf16_kernel<<<512, blk, 0, stream>>>(Wk, wkb, 1048576L);
    f32_to_bf16_kernel<<<512, blk, 0, stream>>>(Wv, wvb, 1048576L);

    // 2) Q projection: q(fp32) @ Wq^T + bq -> Qbf (bf16)
    gemm_bt_kernel<true, true, true, false><<<dim3(8, 64, 1), blk, 0, stream>>>(
        q, wqb, Qbf, bq, 1.0f, 8192, 1024, 1024, 0, 0, 0);

    // 3) K projection: x(fp32) @ Wk^T + bk -> Kbf (bf16)
    gemm_bt_kernel<true, true, true, false><<<dim3(8, 128, 1), blk, 0, stream>>>(
        x, wkb, Kbf, bk, 1.0f, 16384, 1024, 1024, 0, 0, 0);

    // 4) scores = Q @ K^T * (1/32) -> fp32 attention region of d_out
    gemm_bt_kernel<false, false, false, false><<<dim3(16, 8, 8), blk, 0, stream>>>(
        Qbf, Kbf, Sout, nullptr, 0.03125f, 1024, 2048, 1024,
        1048576, 2097152, 2097152);

    // 5) softmax in-place (8192 rows of 2048)
    softmax_kernel<<<8192, blk, 0, stream>>>(Sout, 2048);

    // 6) V projection, transposed epilogue: x(fp32) @ Wv^T + bv -> Vt[8][1024][2048]
    gemm_bt_kernel<true, true, true, true><<<dim3(8, 128, 1), blk, 0, stream>>>(
        x, wvb, Vt, bv, 1.0f, 16384, 1024, 1024, 0, 0, 0);

    // 7) weighted = softmax(S)(fp32, staged->bf16) @ Vt -> fp32 out
    gemm_bt_kernel<true, false, false, false><<<dim3(8, 8, 8), blk, 0, stream>>>(
        Sout, Vt, out, nullptr, 1.0f, 1024, 1024, 2048,
        2097152, 2097152, 1048576);
}

// Round 12
// 446.620 us; speedup vs baseline: 1.1509x; 1.1509x over previous
//
#include <hip/hip_runtime.h>
#include <hip/hip_bf16.h>

typedef __attribute__((ext_vector_type(8))) short short8;
typedef __attribute__((ext_vector_type(4))) short short4v;
typedef __attribute__((ext_vector_type(4))) float f32x4;
using u16 = unsigned short;

__device__ __forceinline__ u16 f2bf(float x) {
    __hip_bfloat16 h = __float2bfloat16(x);
    return *reinterpret_cast<u16*>(&h);
}

__device__ __forceinline__ void async16(void* lds, const void* g) {
    __builtin_amdgcn_global_load_lds((__attribute__((address_space(1))) void*)g,
                                     (__attribute__((address_space(3))) void*)lds,
                                     16, 0, 0);
}

// ---------------------------------------------------------------------------
// fp32 -> bf16 convert (weights only), 8 elems/thread
// ---------------------------------------------------------------------------
__global__ __launch_bounds__(256)
void f32_to_bf16_kernel(const float* __restrict__ in, u16* __restrict__ out, long n) {
    long i = ((long)blockIdx.x * 256 + threadIdx.x) * 8;
    if (i + 8 > n) return;
    float4 a = *(const float4*)(in + i);
    float4 b = *(const float4*)(in + i + 4);
    short8 p;
    p[0] = (short)f2bf(a.x); p[1] = (short)f2bf(a.y);
    p[2] = (short)f2bf(a.z); p[3] = (short)f2bf(a.w);
    p[4] = (short)f2bf(b.x); p[5] = (short)f2bf(b.y);
    p[6] = (short)f2bf(b.z); p[7] = (short)f2bf(b.w);
    *(short8*)(out + i) = p;
}

// ---------------------------------------------------------------------------
// BT-GEMM: C[m][n] = scale * sum_k A[m][k]*B[n][k] (+ bias[n])
// A_F32: A fp32, staged to LDS with on-the-fly bf16 convert (reg ds_write to
//        the same bytes the async16 path fills). B always bf16 via
//        global_load_lds width-16 (m97 structure). 128x128 tile, BK=32.
// KV_FUSED: N=2048 over stacked [Wk;Wv]; bn<1024 -> K row-major to Cv,
//        bn>=1024 -> V transposed into C2 = Vt[8][1024][2048] (batch=row>>11).
// XCD swizzle (T1): blocks sharing an A-panel colocate on one XCD's L2.
// M,N mult of 128; K mult of 32; grid size mult of 8.
// ---------------------------------------------------------------------------
template<bool A_F32, bool OUT_BF16, bool ADD_BIAS, bool KV_FUSED>
__global__ __launch_bounds__(256, 2)
void gemm_bt_kernel(const void* __restrict__ Av, const u16* __restrict__ B,
                    void* __restrict__ Cv, u16* __restrict__ C2,
                    const float* __restrict__ bias, const float* __restrict__ bias2,
                    float scale, int M, int N, int K,
                    long Abatch, long Bbatch, long Cbatch)
{
    __shared__ u16 As[128 * 32];
    __shared__ u16 Bs[128 * 32];

    // --- XCD-aware bijective swizzle (nwg % 8 == 0 for all our grids) ---
    int bx = blockIdx.x, by = blockIdx.y, bz = blockIdx.z;
    {
        const int gx = gridDim.x, gy = gridDim.y;
        const int nwg = gx * gy * gridDim.z;
        if ((nwg & 7) == 0) {
            const int b = bx + gx * (by + gy * bz);
            const int cpx = nwg >> 3;
            const int s = (b & 7) * cpx + (b >> 3);
            bx = s % gx;
            const int t = s / gx;
            by = t % gy;
            bz = t / gy;
        }
    }

    const int tid  = threadIdx.x;
    const int wid  = tid >> 6;
    const int lane = tid & 63;

    B += (long)bz * Bbatch;

    const int bm = by * 128;
    const int bn = bx * 128;

    const int wr = (wid >> 1) * 64;
    const int wc = (wid & 1) * 64;

    f32x4 acc[4][4] = {};

    // staging: thread t covers LDS bytes [t*16, t*16+16) per 4KB half
    // (rows 0..63 then 64..127); row srow, k-elems [scol, scol+8).
    const int srow = tid >> 2;
    const int scol = (tid & 3) * 8;
    const u16*   aptrb = nullptr;
    const float* aptrf = nullptr;
    if constexpr (A_F32) {
        aptrf = (const float*)Av + (long)bz * Abatch + (long)(bm + srow) * K + scol;
    } else {
        aptrb = (const u16*)Av + (long)bz * Abatch + (long)(bm + srow) * K + scol;
    }
    const u16* bptr = B + (long)(bn + srow) * K + scol;
    char* asb = (char*)As + wid * 1024; // wave-uniform base (+lane*16 by HW)
    char* bsb = (char*)Bs + wid * 1024;

    const int lr = lane & 15;
    const int lk = (lane >> 4) * 8;

    const int nk = K >> 5;
    for (int kt = 0; kt < nk; ++kt) {
        const u16* bk = bptr + kt * 32;
        async16(bsb,        bk);
        async16(bsb + 4096, bk + (long)64 * K);
        if constexpr (A_F32) {
            const float* a0 = aptrf + kt * 32;
            float4 u0 = *(const float4*)a0;
            float4 u1 = *(const float4*)(a0 + 4);
            float4 w0 = *(const float4*)(a0 + (long)64 * K);
            float4 w1 = *(const float4*)(a0 + (long)64 * K + 4);
            short8 s0, s1;
            s0[0] = (short)f2bf(u0.x); s0[1] = (short)f2bf(u0.y);
            s0[2] = (short)f2bf(u0.z); s0[3] = (short)f2bf(u0.w);
            s0[4] = (short)f2bf(u1.x); s0[5] = (short)f2bf(u1.y);
            s0[6] = (short)f2bf(u1.z); s0[7] = (short)f2bf(u1.w);
            s1[0] = (short)f2bf(w0.x); s1[1] = (short)f2bf(w0.y);
            s1[2] = (short)f2bf(w0.z); s1[3] = (short)f2bf(w0.w);
            s1[4] = (short)f2bf(w1.x); s1[5] = (short)f2bf(w1.y);
            s1[6] = (short)f2bf(w1.z); s1[7] = (short)f2bf(w1.w);
            *(short8*)((char*)As + tid * 16)        = s0;
            *(short8*)((char*)As + 4096 + tid * 16) = s1;
        } else {
            const u16* ak = aptrb + kt * 32;
            async16(asb,        ak);
            async16(asb + 4096, ak + (long)64 * K);
        }
        __syncthreads();  // drains vmcnt (async16) + lgkmcnt (ds_write)

        short8 af[4], bfr[4];
        #pragma unroll
        for (int i = 0; i < 4; ++i)
            af[i] = *(const short8*)&As[(wr + i * 16 + lr) * 32 + lk];
        #pragma unroll
        for (int j = 0; j < 4; ++j)
            bfr[j] = *(const short8*)&Bs[(wc + j * 16 + lr) * 32 + lk];

        #pragma unroll
        for (int i = 0; i < 4; ++i)
            #pragma unroll
            for (int j = 0; j < 4; ++j)
                acc[i][j] = __builtin_amdgcn_mfma_f32_16x16x32_bf16(
                                af[i], bfr[j], acc[i][j], 0, 0, 0);
        __syncthreads();
    }

    // epilogue: C/D layout col=lane&15, row=(lane>>4)*4+reg  [m89 verified]
    const int r0 = (lane >> 4) * 4;
    const long crow = bm + wr + r0;
    const long ccol = bn + wc + lr;
    if constexpr (KV_FUSED) {
        if (bn < 1024) {
            // K half: row-major bf16 Kbf[16384][1024]
            u16* C = (u16*)Cv;
            #pragma unroll
            for (int i = 0; i < 4; ++i)
                #pragma unroll
                for (int j = 0; j < 4; ++j) {
                    const float bb = bias[ccol + j * 16];
                    #pragma unroll
                    for (int r = 0; r < 4; ++r)
                        C[(crow + i * 16 + r) * 1024L + ccol + j * 16] =
                            f2bf(acc[i][j][r] + bb);
                }
        } else {
            // V half: transposed into Vt[8][1024][2048]
            #pragma unroll
            for (int i = 0; i < 4; ++i) {
                const long row = crow + i * 16;
                const long zb = row >> 11, rr = row & 2047;
                #pragma unroll
                for (int j = 0; j < 4; ++j) {
                    const long feat = ccol - 1024 + j * 16;
                    const float bb = bias2[feat];
                    short4v pk;
                    #pragma unroll
                    for (int r = 0; r < 4; ++r)
                        pk[r] = (short)f2bf(acc[i][j][r] + bb);
                    *(short4v*)(C2 + zb * 2097152 + feat * 2048 + rr) = pk;
                }
            }
        }
    } else if constexpr (OUT_BF16) {
        u16* C = (u16*)Cv + (long)bz * Cbatch;
        #pragma unroll
        for (int i = 0; i < 4; ++i)
            #pragma unroll
            for (int j = 0; j < 4; ++j) {
                float bb = 0.f;
                if constexpr (ADD_BIAS) bb = bias[ccol + j * 16];
                #pragma unroll
                for (int r = 0; r < 4; ++r)
                    C[(crow + i * 16 + r) * (long)N + ccol + j * 16] =
                        f2bf(acc[i][j][r] * scale + bb);
            }
    } else {
        float* C = (float*)Cv + (long)bz * Cbatch;
        #pragma unroll
        for (int i = 0; i < 4; ++i)
            #pragma unroll
            for (int j = 0; j < 4; ++j) {
                float bb = 0.f;
                if constexpr (ADD_BIAS) bb = bias[ccol + j * 16];
                #pragma unroll
                for (int r = 0; r < 4; ++r)
                    C[(crow + i * 16 + r) * (long)N + ccol + j * 16] =
                        acc[i][j][r] * scale + bb;
            }
    }
}

// ---------------------------------------------------------------------------
// row softmax over L=2048, one block per row, in-place fp32.
// ---------------------------------------------------------------------------
__global__ __launch_bounds__(256)
void softmax_kernel(float* __restrict__ S, int L) {
    const long base = (long)blockIdx.x * L;
    float* row = S + base;
    const int t = threadIdx.x;
    const int lane = t & 63, wid = t >> 6;

    float4 v0 = ((const float4*)row)[2 * t];
    float4 v1 = ((const float4*)row)[2 * t + 1];

    float m = fmaxf(fmaxf(fmaxf(v0.x, v0.y), fmaxf(v0.z, v0.w)),
                    fmaxf(fmaxf(v1.x, v1.y), fmaxf(v1.z, v1.w)));
    #pragma unroll
    for (int off = 32; off; off >>= 1) m = fmaxf(m, __shfl_xor(m, off));

    __shared__ float red[8];
    if (lane == 0) red[wid] = m;
    __syncthreads();
    m = fmaxf(fmaxf(red[0], red[1]), fmaxf(red[2], red[3]));

    v0.x = __expf(v0.x - m); v0.y = __expf(v0.y - m);
    v0.z = __expf(v0.z - m); v0.w = __expf(v0.w - m);
    v1.x = __expf(v1.x - m); v1.y = __expf(v1.y - m);
    v1.z = __expf(v1.z - m); v1.w = __expf(v1.w - m);

    float s = ((v0.x + v0.y) + (v0.z + v0.w)) + ((v1.x + v1.y) + (v1.z + v1.w));
    #pragma unroll
    for (int off = 32; off; off >>= 1) s += __shfl_xor(s, off);
    if (lane == 0) red[4 + wid] = s;
    __syncthreads();
    s = (red[4] + red[5]) + (red[6] + red[7]);

    const float inv = 1.0f / s;
    v0.x *= inv; v0.y *= inv; v0.z *= inv; v0.w *= inv;
    v1.x *= inv; v1.y *= inv; v1.z *= inv; v1.w *= inv;

    ((float4*)row)[2 * t]     = v0;
    ((float4*)row)[2 * t + 1] = v1;
}

// ---------------------------------------------------------------------------
// launch — peak workspace 56,623,104 bytes (u16 offsets).
//   wqb@0  wkb@1,048,576  wvb@2,097,152  (wkb,wvb contiguous = stacked KV B)
//   Qbf@3,145,728 (8,388,608)   [dead after QK]
//   Kbf@11,534,336 (16,777,216) [dead after QK... but needed until QK done]
//   Vt @3,145,728..19,922,944 — WAIT: Vt must coexist with Kbf during QK?
//   No: fused KV writes BOTH Kbf and Vt before QK. Vt must NOT alias Kbf.
//   Layout: Vt@28,311,552 (16,777,216) → peak 90 MB? ws proved ≥56.6 MB only.
//   Safe alternative: Vt@3,145,728 overlaps Qbf(8.4M)+Kbf head — INVALID now.
//   Resolution: Qbf stays, Kbf@11,534,336, Vt@28,311,552 → peak 45,088,768 u16
//   = 90,177,536 B. UNKNOWN if ws fits. Use PROVEN-SAFE layout instead:
//   keep V-proj as part of fused kernel but write Vt into the region AFTER
//   Kbf: Vt@28,311,552. Total 90.2 MB — risk. Fallback decision: out region!
//   Sout (attention, 64 MB f32) is not written until QK; Vt (32 MB) cannot go
//   there (QK overwrites). FINAL: accept 90.2 MB only if ws allows; we know
//   107 MB faulted, 56.6 passed. To stay ≤56.6: drop Qbf region reuse — run
//   fused KV FIRST, then Q-proj into the region AFTER Vt is consumed? Q is
//   needed for QK which needs Kbf+Vt live... Instead: revert V to row-major
//   INTO the weighted region of d_out (32 MB of the 32 MB weighted area,
//   bf16 in f32 slots? weighted is 8M floats = 32 MB; Vbf bf16 = 32 MB ✓),
//   transpose-read in PV? Too complex. SIMPLEST: fused KV writes Vt into
//   ws at 28,311,552 → peak 90.2 MB. 107 MB faulted; 90.2 may fit (in_npz
//   was 105 MB, out 92 MB — ws likely ≥ out size 92 MB). Take the risk with
//   fallback documented: if core dump, next round splits V-proj after QK.
// ---------------------------------------------------------------------------
extern "C" void kernel_launch(void* const* d_in, const int* in_sizes, int n_in,
                              void* d_out, int out_size, void* d_ws, size_t ws_size,
                              hipStream_t stream) {
    const float* x  = (const float*)d_in[0];   // [8,2048,1024]
    const float* q  = (const float*)d_in[1];   // [8,1024,1024]
    const float* Wq = (const float*)d_in[2];
    const float* bq = (const float*)d_in[3];
    const float* Wk = (const float*)d_in[4];
    const float* bk = (const float*)d_in[5];
    const float* Wv = (const float*)d_in[6];
    const float* bv = (const float*)d_in[7];
    float* out = (float*)d_out;  // weighted [8,1024,1024] ++ attention [8,1024,2048]

    u16* ws  = (u16*)d_ws;
    u16* wqb = ws;
    u16* wkb = ws + 1048576;    // stacked [Wk;Wv] starts here
    u16* wvb = ws + 2097152;
    u16* Qbf = ws + 3145728;    //  8,388,608 u16
    u16* Kbf = ws + 11534336;   // 16,777,216 u16
    u16* Vt  = ws + 28311552;   // 16,777,216 u16  (peak 90,177,536 B)

    float* Sout = out + 8388608;  // attention region of d_out

    dim3 blk(256);

    // 1) weights -> bf16
    f32_to_bf16_kernel<<<512, blk, 0, stream>>>(Wq, wqb, 1048576L);
    f32_to_bf16_kernel<<<512, blk, 0, stream>>>(Wk, wkb, 1048576L);
    f32_to_bf16_kernel<<<512, blk, 0, stream>>>(Wv, wvb, 1048576L);

    // 2) Q projection: q(fp32) @ Wq^T + bq -> Qbf
    gemm_bt_kernel<true, true, true, false><<<dim3(8, 64, 1), blk, 0, stream>>>(
        q, wqb, Qbf, nullptr, bq, nullptr, 1.0f, 8192, 1024, 1024, 0, 0, 0);

    // 3) fused K+V projection: x(fp32) @ [Wk;Wv]^T -> Kbf (row-major) + Vt (transposed)
    gemm_bt_kernel<true, true, true, true><<<dim3(16, 128, 1), blk, 0, stream>>>(
        x, wkb, Kbf, Vt, bk, bv, 1.0f, 16384, 2048, 1024, 0, 0, 0);

    // 4) scores = Q @ K^T * (1/32) -> fp32 attention region
    gemm_bt_kernel<false, false, false, false><<<dim3(16, 8, 8), blk, 0, stream>>>(
        Qbf, Kbf, Sout, nullptr, nullptr, nullptr, 0.03125f, 1024, 2048, 1024,
        1048576, 2097152, 2097152);

    // 5) softmax in-place (8192 rows of 2048)
    softmax_kernel<<<8192, blk, 0, stream>>>(Sout, 2048);

    // 6) weighted = softmax(S)(fp32, staged->bf16) @ Vt -> fp32 out
    gemm_bt_kernel<true, false, false, false><<<dim3(8, 8, 8), blk, 0, stream>>>(
        Sout, Vt, out, nullptr, nullptr, nullptr, 1.0f, 1024, 1024, 2048,
        2097152, 2097152, 1048576);
}

// Round 13
// 413.222 us; speedup vs baseline: 1.2439x; 1.0808x over previous
//
#include <hip/hip_runtime.h>
#include <hip/hip_bf16.h>

typedef __attribute__((ext_vector_type(8))) short short8;
typedef __attribute__((ext_vector_type(4))) short short4v;
typedef __attribute__((ext_vector_type(4))) float f32x4;
using u16 = unsigned short;

__device__ __forceinline__ u16 f2bf(float x) {
    __hip_bfloat16 h = __float2bfloat16(x);
    return *reinterpret_cast<u16*>(&h);
}

__device__ __forceinline__ void async16(void* lds, const void* g) {
    __builtin_amdgcn_global_load_lds((__attribute__((address_space(1))) void*)g,
                                     (__attribute__((address_space(3))) void*)lds,
                                     16, 0, 0);
}

// ---------------------------------------------------------------------------
// fp32 -> bf16 convert, 8 elems/thread, vectorized
// ---------------------------------------------------------------------------
__global__ __launch_bounds__(256)
void f32_to_bf16_kernel(const float* __restrict__ in, u16* __restrict__ out, long n) {
    long i = ((long)blockIdx.x * 256 + threadIdx.x) * 8;
    if (i + 8 > n) return;
    float4 a = *(const float4*)(in + i);
    float4 b = *(const float4*)(in + i + 4);
    short8 p;
    p[0] = (short)f2bf(a.x); p[1] = (short)f2bf(a.y);
    p[2] = (short)f2bf(a.z); p[3] = (short)f2bf(a.w);
    p[4] = (short)f2bf(b.x); p[5] = (short)f2bf(b.y);
    p[6] = (short)f2bf(b.z); p[7] = (short)f2bf(b.w);
    *(short8*)(out + i) = p;
}

// ---------------------------------------------------------------------------
// BT-GEMM: C[m][n] = scale * sum_k A[m][k]*B[n][k] (+ bias[n])
// A,B bf16 row-major, both staged via global_load_lds width-16 (m97 form).
// 128x128 tile, BK=32, 4 waves. KV_FUSED: N=2048 over stacked [Wk;Wv];
// bn<1024 -> K row-major to Cv, bn>=1024 -> V transposed into
// C2 = Vt[8][1024][2048] (batch=row>>11). XCD-aware bijective swizzle (T1).
// M,N mult of 128; K mult of 32; grid size mult of 8.
// ---------------------------------------------------------------------------
template<bool OUT_BF16, bool ADD_BIAS, bool KV_FUSED>
__global__ __launch_bounds__(256, 2)
void gemm_bt_kernel(const u16* __restrict__ A, const u16* __restrict__ B,
                    void* __restrict__ Cv, u16* __restrict__ C2,
                    const float* __restrict__ bias, const float* __restrict__ bias2,
                    float scale, int M, int N, int K,
                    long Abatch, long Bbatch, long Cbatch)
{
    __shared__ u16 As[128 * 32];
    __shared__ u16 Bs[128 * 32];

    // --- XCD-aware bijective swizzle (all grids have nwg % 8 == 0) ---
    int bx = blockIdx.x, by = blockIdx.y, bz = blockIdx.z;
    {
        const int gx = gridDim.x, gy = gridDim.y;
        const int nwg = gx * gy * gridDim.z;
        if ((nwg & 7) == 0) {
            const int b = bx + gx * (by + gy * bz);
            const int cpx = nwg >> 3;
            const int s = (b & 7) * cpx + (b >> 3);
            bx = s % gx;
            const int t = s / gx;
            by = t % gy;
            bz = t / gy;
        }
    }

    const int tid  = threadIdx.x;
    const int wid  = tid >> 6;
    const int lane = tid & 63;

    A += (long)bz * Abatch;
    B += (long)bz * Bbatch;

    const int bm = by * 128;
    const int bn = bx * 128;

    const int wr = (wid >> 1) * 64;
    const int wc = (wid & 1) * 64;

    f32x4 acc[4][4] = {};

    // staging: thread t covers LDS bytes [t*16, t*16+16) per 4KB half
    // (rows 0..63 then 64..127); row srow, k-elems [scol, scol+8).
    const int srow = tid >> 2;
    const int scol = (tid & 3) * 8;
    const u16* aptr = A + (long)(bm + srow) * K + scol;
    const u16* bptr = B + (long)(bn + srow) * K + scol;
    char* asb = (char*)As + wid * 1024; // wave-uniform base (+lane*16 by HW)
    char* bsb = (char*)Bs + wid * 1024;

    const int lr = lane & 15;
    const int lk = (lane >> 4) * 8;

    const int nk = K >> 5;
    for (int kt = 0; kt < nk; ++kt) {
        const u16* ak = aptr + kt * 32;
        const u16* bk = bptr + kt * 32;
        async16(asb,        ak);
        async16(asb + 4096, ak + (long)64 * K);
        async16(bsb,        bk);
        async16(bsb + 4096, bk + (long)64 * K);
        __syncthreads();   // compiler drains vmcnt before s_barrier

        short8 af[4], bfr[4];
        #pragma unroll
        for (int i = 0; i < 4; ++i)
            af[i] = *(const short8*)&As[(wr + i * 16 + lr) * 32 + lk];
        #pragma unroll
        for (int j = 0; j < 4; ++j)
            bfr[j] = *(const short8*)&Bs[(wc + j * 16 + lr) * 32 + lk];

        #pragma unroll
        for (int i = 0; i < 4; ++i)
            #pragma unroll
            for (int j = 0; j < 4; ++j)
                acc[i][j] = __builtin_amdgcn_mfma_f32_16x16x32_bf16(
                                af[i], bfr[j], acc[i][j], 0, 0, 0);
        __syncthreads();
    }

    // epilogue: C/D layout col=lane&15, row=(lane>>4)*4+reg  [m89 verified]
    const int r0 = (lane >> 4) * 4;
    const long crow = bm + wr + r0;
    const long ccol = bn + wc + lr;
    if constexpr (KV_FUSED) {
        if (bn < 1024) {
            // K half: row-major bf16 Kbf[16384][1024]
            u16* C = (u16*)Cv;
            #pragma unroll
            for (int i = 0; i < 4; ++i)
                #pragma unroll
                for (int j = 0; j < 4; ++j) {
                    const float bb = bias[ccol + j * 16];
                    #pragma unroll
                    for (int r = 0; r < 4; ++r)
                        C[(crow + i * 16 + r) * 1024L + ccol + j * 16] =
                            f2bf(acc[i][j][r] + bb);
                }
        } else {
            // V half: transposed into Vt[8][1024][2048]
            #pragma unroll
            for (int i = 0; i < 4; ++i) {
                const long row = crow + i * 16;
                const long zb = row >> 11, rr = row & 2047;
                #pragma unroll
                for (int j = 0; j < 4; ++j) {
                    const long feat = ccol - 1024 + j * 16;
                    const float bb = bias2[feat];
                    short4v pk;
                    #pragma unroll
                    for (int r = 0; r < 4; ++r)
                        pk[r] = (short)f2bf(acc[i][j][r] + bb);
                    *(short4v*)(C2 + zb * 2097152 + feat * 2048 + rr) = pk;
                }
            }
        }
    } else if constexpr (OUT_BF16) {
        u16* C = (u16*)Cv + (long)bz * Cbatch;
        #pragma unroll
        for (int i = 0; i < 4; ++i)
            #pragma unroll
            for (int j = 0; j < 4; ++j) {
                float bb = 0.f;
                if constexpr (ADD_BIAS) bb = bias[ccol + j * 16];
                #pragma unroll
                for (int r = 0; r < 4; ++r)
                    C[(crow + i * 16 + r) * (long)N + ccol + j * 16] =
                        f2bf(acc[i][j][r] * scale + bb);
            }
    } else {
        float* C = (float*)Cv + (long)bz * Cbatch;
        #pragma unroll
        for (int i = 0; i < 4; ++i)
            #pragma unroll
            for (int j = 0; j < 4; ++j) {
                float bb = 0.f;
                if constexpr (ADD_BIAS) bb = bias[ccol + j * 16];
                #pragma unroll
                for (int r = 0; r < 4; ++r)
                    C[(crow + i * 16 + r) * (long)N + ccol + j * 16] =
                        acc[i][j][r] * scale + bb;
            }
    }
}

// ---------------------------------------------------------------------------
// row softmax over L=2048, one block per row, in-place fp32 + bf16 P copy.
// ---------------------------------------------------------------------------
__global__ __launch_bounds__(256)
void softmax_kernel(float* __restrict__ S, u16* __restrict__ P, int L) {
    const long base = (long)blockIdx.x * L;
    float* row = S + base;
    const int t = threadIdx.x;
    const int lane = t & 63, wid = t >> 6;

    float4 v0 = ((const float4*)row)[2 * t];
    float4 v1 = ((const float4*)row)[2 * t + 1];

    float m = fmaxf(fmaxf(fmaxf(v0.x, v0.y), fmaxf(v0.z, v0.w)),
                    fmaxf(fmaxf(v1.x, v1.y), fmaxf(v1.z, v1.w)));
    #pragma unroll
    for (int off = 32; off; off >>= 1) m = fmaxf(m, __shfl_xor(m, off));

    __shared__ float red[8];
    if (lane == 0) red[wid] = m;
    __syncthreads();
    m = fmaxf(fmaxf(red[0], red[1]), fmaxf(red[2], red[3]));

    v0.x = __expf(v0.x - m); v0.y = __expf(v0.y - m);
    v0.z = __expf(v0.z - m); v0.w = __expf(v0.w - m);
    v1.x = __expf(v1.x - m); v1.y = __expf(v1.y - m);
    v1.z = __expf(v1.z - m); v1.w = __expf(v1.w - m);

    float s = ((v0.x + v0.y) + (v0.z + v0.w)) + ((v1.x + v1.y) + (v1.z + v1.w));
    #pragma unroll
    for (int off = 32; off; off >>= 1) s += __shfl_xor(s, off);
    if (lane == 0) red[4 + wid] = s;
    __syncthreads();
    s = (red[4] + red[5]) + (red[6] + red[7]);

    const float inv = 1.0f / s;
    v0.x *= inv; v0.y *= inv; v0.z *= inv; v0.w *= inv;
    v1.x *= inv; v1.y *= inv; v1.z *= inv; v1.w *= inv;

    ((float4*)row)[2 * t]     = v0;
    ((float4*)row)[2 * t + 1] = v1;

    short8 p;
    p[0] = (short)f2bf(v0.x); p[1] = (short)f2bf(v0.y);
    p[2] = (short)f2bf(v0.z); p[3] = (short)f2bf(v0.w);
    p[4] = (short)f2bf(v1.x); p[5] = (short)f2bf(v1.y);
    p[6] = (short)f2bf(v1.z); p[7] = (short)f2bf(v1.w);
    *(short8*)(P + base + 8 * t) = p;
}

// ---------------------------------------------------------------------------
// launch — ws peak 90,177,536 B (proven OK in round 12). d_out doubles as
// scratch for the bf16 input copies (dead regions at that point):
//   xbf (33.5 MB) lives in the attention area until QK overwrites it;
//   qbf (16.8 MB) lives in the weighted area until PV overwrites it;
//   Pbf (33.5 MB) lives in ws over dead Qbf+Kbf-head after QK.
// Order: conv x,q,W -> Qproj -> fusedKV -> QK -> softmax(+P) -> PV.
// ---------------------------------------------------------------------------
extern "C" void kernel_launch(void* const* d_in, const int* in_sizes, int n_in,
                              void* d_out, int out_size, void* d_ws, size_t ws_size,
                              hipStream_t stream) {
    const float* x  = (const float*)d_in[0];   // [8,2048,1024]
    const float* q  = (const float*)d_in[1];   // [8,1024,1024]
    const float* Wq = (const float*)d_in[2];
    const float* bq = (const float*)d_in[3];
    const float* Wk = (const float*)d_in[4];
    const float* bk = (const float*)d_in[5];
    const float* Wv = (const float*)d_in[6];
    const float* bv = (const float*)d_in[7];
    float* out = (float*)d_out;  // weighted [8,1024,1024] ++ attention [8,1024,2048]

    u16* ws  = (u16*)d_ws;
    u16* wqb = ws;              // 1,048,576 u16
    u16* wkb = ws + 1048576;    // stacked [Wk;Wv]
    u16* wvb = ws + 2097152;
    u16* Qbf = ws + 3145728;    //  8,388,608 u16  [dead after QK]
    u16* Kbf = ws + 11534336;   // 16,777,216 u16  [dead after QK]
    u16* Pbf = ws + 3145728;    // 16,777,216 u16  (over dead Qbf+Kbf head)
    u16* Vt  = ws + 28311552;   // 16,777,216 u16

    float* Sout = out + 8388608;        // attention region of d_out
    u16*   xbf  = (u16*)Sout;           // 16,777,216 u16 in attention area
    u16*   qbf  = (u16*)out;            //  8,388,608 u16 in weighted area

    dim3 blk(256);

    // 1) converts: inputs + weights -> bf16
    f32_to_bf16_kernel<<<8192, blk, 0, stream>>>(x,  xbf, 16777216L);
    f32_to_bf16_kernel<<<4096, blk, 0, stream>>>(q,  qbf,  8388608L);
    f32_to_bf16_kernel<<<512,  blk, 0, stream>>>(Wq, wqb,  1048576L);
    f32_to_bf16_kernel<<<512,  blk, 0, stream>>>(Wk, wkb,  1048576L);
    f32_to_bf16_kernel<<<512,  blk, 0, stream>>>(Wv, wvb,  1048576L);

    // 2) Q projection: qbf @ Wq^T + bq -> Qbf
    gemm_bt_kernel<true, true, false><<<dim3(8, 64, 1), blk, 0, stream>>>(
        qbf, wqb, Qbf, nullptr, bq, nullptr, 1.0f, 8192, 1024, 1024, 0, 0, 0);

    // 3) fused K+V projection: xbf @ [Wk;Wv]^T -> Kbf (row-major) + Vt (transposed)
    gemm_bt_kernel<true, true, true><<<dim3(16, 128, 1), blk, 0, stream>>>(
        xbf, wkb, Kbf, Vt, bk, bv, 1.0f, 16384, 2048, 1024, 0, 0, 0);

    // 4) scores = Q @ K^T * (1/32) -> fp32 attention region (overwrites xbf)
    gemm_bt_kernel<false, false, false><<<dim3(16, 8, 8), blk, 0, stream>>>(
        Qbf, Kbf, Sout, nullptr, nullptr, nullptr, 0.03125f, 1024, 2048, 1024,
        1048576, 2097152, 2097152);

    // 5) softmax in-place + bf16 P -> Pbf (over dead Q/K)
    softmax_kernel<<<8192, blk, 0, stream>>>(Sout, Pbf, 2048);

    // 6) weighted = P @ Vt -> fp32 out (overwrites qbf)
    gemm_bt_kernel<false, false, false><<<dim3(8, 8, 8), blk, 0, stream>>>(
        Pbf, Vt, out, nullptr, nullptr, nullptr, 1.0f, 1024, 1024, 2048,
        2097152, 2097152, 1048576);
}